// Round 20
// baseline (98.860 us; speedup 1.0000x reference)
//
#include <hip/hip_runtime.h>
#include <math.h>

// Problem constants (B, D, C) from the reference.
#define NB 4096
#define ND 3072
#define NC 10
#define NM 9   // C-1
#define NF (ND / 4)   // 768 float4 per Wt row

static constexpr float kEps      = 0.1f;
static constexpr float kNumStab  = 1e-6f;
static constexpr float kAlpha    = 1.0f - (float)NC * kNumStab;  // 1 - C*num_stab
static constexpr float kInvSqrtC = 0.31622776601683794f;         // 1/sqrt(10)

// ---------------------------------------------------------------------------
// R19 post-mortem: two source-level pipelining attempts moved main by ~1 µs.
// R12 proved hipcc SINKS upfront global loads to their use sites (24 loads
// issued, VGPR stayed 64) — both experiments were silently reverted by the
// scheduler. This round pins the schedule: ALL 24 data float4 loads issued in
// the prologue, then __builtin_amdgcn_sched_barrier(0) (scheduler may not
// move instructions across it). 24 KB/wave of HBM traffic in flight before
// the first FMA; Little's law needs only ~9 KB/CU for full BW. VGPR ~210
// fits the 256-cap of (256,2); 8 waves/CU unchanged. prep_kernel unchanged.
// ---------------------------------------------------------------------------

__global__ __launch_bounds__(256) void prep_kernel(
        const float* __restrict__ W, float* __restrict__ Wt,
        float* __restrict__ G, float* __restrict__ out) {
    if (blockIdx.x < 30) {
        // ---- transpose: output float4 id c covers rows d=4m..4m+3, class k.
        if (blockIdx.x == 0 && threadIdx.x == 0) out[0] = 0.0f;
        const int c = blockIdx.x * 256 + threadIdx.x;   // 7680 = 30*256 exactly
        const int k = c / NF;
        const int m = c - k * NF;
        float4 v;
        v.x = W[(4 * m + 0) * NC + k];
        v.y = W[(4 * m + 1) * NC + k];
        v.z = W[(4 * m + 2) * NC + k];
        v.w = W[(4 * m + 3) * NC + k];
        reinterpret_cast<float4*>(Wt)[c] = v;
    } else {
        // ---- Gram upper-triangle entry (j,k) straight from W (L2-hot).
        int e = blockIdx.x - 30, j = 0;
        while (e >= NC - j) { e -= NC - j; ++j; }
        const int k = j + e;
        float acc = 0.0f;
        for (int d = threadIdx.x; d < ND; d += 256)
            acc = fmaf(W[d * NC + j], W[d * NC + k], acc);
        #pragma unroll
        for (int off = 32; off > 0; off >>= 1) acc += __shfl_xor(acc, off, 64);
        __shared__ float part[4];
        if ((threadIdx.x & 63) == 0) part[threadIdx.x >> 6] = acc;
        __syncthreads();
        if (threadIdx.x == 0) {
            const float g = part[0] + part[1] + part[2] + part[3];
            G[j * NC + k] = g;
            G[k * NC + j] = g;
        }
    }
}

// Main: 512 blocks x 256 threads; wave owns 2 samples. All data loads issued
// up front and PINNED with sched_barrier(0); Wt double-buffered per chunk.
__global__ __launch_bounds__(256, 2) void main_kernel(
        const float* __restrict__ data, const float* __restrict__ Wt,
        const float* __restrict__ G, float* __restrict__ out) {
    __shared__ float Gs[100];
    __shared__ float regs[8];

    const int tid  = threadIdx.x;
    const int lane = tid & 63;
    const int wv   = tid >> 6;

    if (tid < 100) Gs[tid] = G[tid];
    __syncthreads();

    const int s0 = blockIdx.x * 8 + wv * 2;          // this wave's 2 samples
    const float4* d0 = reinterpret_cast<const float4*>(data) + (size_t)s0 * NF;
    const float4* d1 = d0 + NF;
    const float4* Wt4 = reinterpret_cast<const float4*>(Wt);

    // Prologue: ALL 24 data loads issued (24 KB/wave in flight) + Wt chunk 0.
    float4 xb0[12], xb1[12];
    #pragma unroll
    for (int p = 0; p < 12; ++p) {
        xb0[p] = d0[p * 64 + lane];
        xb1[p] = d1[p * 64 + lane];
    }
    float4 wq[2][NC];
    #pragma unroll
    for (int k = 0; k < NC; ++k) wq[0][k] = Wt4[k * NF + lane];
    // The scheduler may not move any instruction across this fence: the loads
    // above are ISSUED before any FMA below (defeats load-sinking, cf. R12).
    __builtin_amdgcn_sched_barrier(0);

    float acc[2][NC];
    #pragma unroll
    for (int s = 0; s < 2; ++s)
        #pragma unroll
        for (int k = 0; k < NC; ++k) acc[s][k] = 0.0f;

    #pragma unroll
    for (int it = 0; it < 12; ++it) {
        const int cur = it & 1, nxt = cur ^ 1;     // static after unroll
        if (it < 11) {                             // prefetch next Wt chunk
            const int fn = (it + 1) * 64 + lane;
            #pragma unroll
            for (int k = 0; k < NC; ++k) wq[nxt][k] = Wt4[k * NF + fn];
        }
        const float4 x0 = xb0[it], x1 = xb1[it];   // static index (reg-resident)
        #pragma unroll
        for (int k = 0; k < NC; ++k) {
            const float4 wt = wq[cur][k];
            acc[0][k] = fmaf(x0.x, wt.x, acc[0][k]);
            acc[0][k] = fmaf(x0.y, wt.y, acc[0][k]);
            acc[0][k] = fmaf(x0.z, wt.z, acc[0][k]);
            acc[0][k] = fmaf(x0.w, wt.w, acc[0][k]);
            acc[1][k] = fmaf(x1.x, wt.x, acc[1][k]);
            acc[1][k] = fmaf(x1.y, wt.y, acc[1][k]);
            acc[1][k] = fmaf(x1.z, wt.z, acc[1][k]);
            acc[1][k] = fmaf(x1.w, wt.w, acc[1][k]);
        }
    }

    // In-wave butterfly: every lane ends with full z[10] for both samples.
    #pragma unroll
    for (int s = 0; s < 2; ++s)
        #pragma unroll
        for (int k = 0; k < NC; ++k) {
            float v = acc[s][k];
            #pragma unroll
            for (int off = 32; off > 0; off >>= 1) v += __shfl_xor(v, off, 64);
            acc[s][k] = v;
        }

    // Analytic epilogue: lane 0 -> sample s0, lane 1 -> sample s0+1.
    if (lane < 2) {
        float z[NC];
        #pragma unroll
        for (int k = 0; k < NC; ++k) z[k] = (lane == 0) ? acc[0][k] : acc[1][k];

        float zm = z[0];
        #pragma unroll
        for (int k = 1; k < NC; ++k) zm = fmaxf(zm, z[k]);
        float e[NC], Zs = 0.0f;
        #pragma unroll
        for (int k = 0; k < NC; ++k) { e[k] = expf(z[k] - zm); Zs += e[k]; }
        const float inv = 1.0f / Zs;

        float sg[NC], p[NC], sq[NC], u[NC];
        #pragma unroll
        for (int k = 0; k < NC; ++k) {
            sg[k] = e[k] * inv;                 // softmax probs (sigma)
            p[k]  = kAlpha * sg[k] + kNumStab;  // stabilized probs
            sq[k] = sqrtf(p[k]);                // s
            u[k]  = sg[k] / sq[k];              // sigma / s
        }
        const float qd = 1.0f - sq[NM];

        // v = G*sigma, t = sigma^T G sigma
        float v[NC], t = 0.0f;
        #pragma unroll
        for (int k = 0; k < NC; ++k) {
            float a = 0.0f;
            #pragma unroll
            for (int j = 0; j < NC; ++j) a = fmaf(Gs[k * NC + j], sg[j], a);
            v[k] = a;
            t = fmaf(sg[k], a, t);
        }
        const float vM = v[NM], uM = u[NM];
        const float QMM = Gs[NC * NC - 1] - 2.0f * vM + t;

        float sumJ = 0.0f;
        #pragma unroll
        for (int i = 0; i < NM; ++i) {
            const float Qii = Gs[i * NC + i] - 2.0f * v[i] + t;
            const float QiM = Gs[i * NC + NM] - v[i] - vM + t;
            const float r = sq[i] / qd;
            sumJ += u[i] * u[i] * Qii
                  + 2.0f * u[i] * uM * r * QiM
                  + uM * uM * r * r * QMM;
        }
        const float jn = (kAlpha / qd) * sqrtf(fmaxf(sumJ, 0.0f));

        float ssum = 0.0f;
        #pragma unroll
        for (int k = 0; k < NC; ++k) ssum += sq[k];
        const float ac = fminf(1.0f, fmaxf(-1.0f, ssum * kInvSqrtC));
        const float delta = 2.0f * acosf(ac);

        float psum = 0.0f;
        #pragma unroll
        for (int k = 0; k < NM; ++k) psum += p[k];
        const float rho = (2.0f * qd - psum) / qd;

        const float a = jn - delta / (rho * kEps);
        regs[wv * 2 + lane] = (a > 0.0f) ? a : expm1f(a);
    }
    __syncthreads();
    if (tid == 0) {
        float bs = 0.0f;
        #pragma unroll
        for (int i = 0; i < 8; ++i) bs += regs[i];
        atomicAdd(out, bs * (1.0f / (float)NB));
    }
}

extern "C" void kernel_launch(void* const* d_in, const int* in_sizes, int n_in,
                              void* d_out, int out_size, void* d_ws, size_t ws_size,
                              hipStream_t stream) {
    const float* data = (const float*)d_in[0];
    const float* W    = (const float*)d_in[1];
    float* out = (float*)d_out;
    float* Wt  = (float*)d_ws;            // NC*ND floats (120 KB)
    float* G   = Wt + NC * ND;            // 100 floats

    // prep zeroes out (replaces hipMemsetAsync), transposes W, computes Gram.
    prep_kernel<<<30 + (NC * (NC + 1)) / 2, 256, 0, stream>>>(W, Wt, G, out);
    main_kernel<<<NB / 8, 256, 0, stream>>>(data, Wt, G, out);
}

// Round 21
// 97.886 us; speedup vs baseline: 1.0099x; 1.0099x over previous
//
#include <hip/hip_runtime.h>
#include <math.h>

// Problem constants (B, D, C) from the reference.
#define NB 4096
#define ND 3072
#define NC 10
#define NM 9   // C-1
#define NF (ND / 4)   // 768 float4 per Wt row

static constexpr float kEps      = 0.1f;
static constexpr float kNumStab  = 1e-6f;
static constexpr float kAlpha    = 1.0f - (float)NC * kNumStab;  // 1 - C*num_stab
static constexpr float kInvSqrtC = 0.31622776601683794f;         // 1/sqrt(10)

// ---------------------------------------------------------------------------
// R20 post-mortem: load-schedule pinning hurt (+3 µs) — third failed latency
// theory. Revised model: main is L1-MISS-CONCURRENCY bound. Each wave streams
// the full 120 KB Wt (1920 lines) per sample-pair; waves drift out of phase,
// so every wave's Wt reads miss the 32 KB L1 and queue on L2 independently:
// ~18 K line-misses/CU at ~10 B/cyc effective = the observed ~36-39 µs.
// Fix (1-line-class change on the best R19 body): __syncthreads() per
// iteration LOCK-STEPS the block's 4 waves onto the same 10 KB Wt chunk —
// one wave's L2 miss becomes the others' L1 hits (2 blocks/CU -> 20 KB
// concurrent working set, fits L1). wq double-buffer dropped (lock-step
// makes cross-iter Wt prefetch moot); depth-4 data rotation kept.
// ---------------------------------------------------------------------------

__global__ __launch_bounds__(256) void prep_kernel(
        const float* __restrict__ W, float* __restrict__ Wt,
        float* __restrict__ G, float* __restrict__ out) {
    if (blockIdx.x < 30) {
        // ---- transpose: output float4 id c covers rows d=4m..4m+3, class k.
        if (blockIdx.x == 0 && threadIdx.x == 0) out[0] = 0.0f;
        const int c = blockIdx.x * 256 + threadIdx.x;   // 7680 = 30*256 exactly
        const int k = c / NF;
        const int m = c - k * NF;
        float4 v;
        v.x = W[(4 * m + 0) * NC + k];
        v.y = W[(4 * m + 1) * NC + k];
        v.z = W[(4 * m + 2) * NC + k];
        v.w = W[(4 * m + 3) * NC + k];
        reinterpret_cast<float4*>(Wt)[c] = v;
    } else {
        // ---- Gram upper-triangle entry (j,k) straight from W (L2-hot).
        int e = blockIdx.x - 30, j = 0;
        while (e >= NC - j) { e -= NC - j; ++j; }
        const int k = j + e;
        float acc = 0.0f;
        for (int d = threadIdx.x; d < ND; d += 256)
            acc = fmaf(W[d * NC + j], W[d * NC + k], acc);
        #pragma unroll
        for (int off = 32; off > 0; off >>= 1) acc += __shfl_xor(acc, off, 64);
        __shared__ float part[4];
        if ((threadIdx.x & 63) == 0) part[threadIdx.x >> 6] = acc;
        __syncthreads();
        if (threadIdx.x == 0) {
            const float g = part[0] + part[1] + part[2] + part[3];
            G[j * NC + k] = g;
            G[k * NC + j] = g;
        }
    }
}

// Main: 512 blocks x 256 threads; wave owns 2 samples. Lock-stepped Wt reads
// (per-iteration __syncthreads) + depth-4 rolling data prefetch.
__global__ __launch_bounds__(256, 2) void main_kernel(
        const float* __restrict__ data, const float* __restrict__ Wt,
        const float* __restrict__ G, float* __restrict__ out) {
    __shared__ float Gs[100];
    __shared__ float regs[8];

    const int tid  = threadIdx.x;
    const int lane = tid & 63;
    const int wv   = tid >> 6;

    if (tid < 100) Gs[tid] = G[tid];
    __syncthreads();

    const int s0 = blockIdx.x * 8 + wv * 2;          // this wave's 2 samples
    const float4* d0 = reinterpret_cast<const float4*>(data) + (size_t)s0 * NF;
    const float4* d1 = d0 + NF;
    const float4* Wt4 = reinterpret_cast<const float4*>(Wt);

    float acc[2][NC];
    #pragma unroll
    for (int s = 0; s < 2; ++s)
        #pragma unroll
        for (int k = 0; k < NC; ++k) acc[s][k] = 0.0f;

    // Prologue: 4 iterations of data in flight.
    float4 xb0[4], xb1[4];
    #pragma unroll
    for (int p = 0; p < 4; ++p) {
        xb0[p] = d0[p * 64 + lane];
        xb1[p] = d1[p * 64 + lane];
    }

    #pragma unroll
    for (int it = 0; it < 12; ++it) {
        // Lock-step the block's 4 waves onto the same Wt chunk: first toucher
        // misses to L2, the rest hit L1 (the whole point of this round).
        __syncthreads();
        const int f = it * 64 + lane;
        float4 wq[NC];
        #pragma unroll
        for (int k = 0; k < NC; ++k) wq[k] = Wt4[k * NF + f];

        const int slot = it & 3;                   // static after unroll
        const float4 x0 = xb0[slot], x1 = xb1[slot];
        if (it < 8) {                              // refill 4 iterations ahead
            xb0[slot] = d0[(it + 4) * 64 + lane];
            xb1[slot] = d1[(it + 4) * 64 + lane];
        }
        #pragma unroll
        for (int k = 0; k < NC; ++k) {
            const float4 wt = wq[k];
            acc[0][k] = fmaf(x0.x, wt.x, acc[0][k]);
            acc[0][k] = fmaf(x0.y, wt.y, acc[0][k]);
            acc[0][k] = fmaf(x0.z, wt.z, acc[0][k]);
            acc[0][k] = fmaf(x0.w, wt.w, acc[0][k]);
            acc[1][k] = fmaf(x1.x, wt.x, acc[1][k]);
            acc[1][k] = fmaf(x1.y, wt.y, acc[1][k]);
            acc[1][k] = fmaf(x1.z, wt.z, acc[1][k]);
            acc[1][k] = fmaf(x1.w, wt.w, acc[1][k]);
        }
    }

    // In-wave butterfly: every lane ends with full z[10] for both samples.
    #pragma unroll
    for (int s = 0; s < 2; ++s)
        #pragma unroll
        for (int k = 0; k < NC; ++k) {
            float v = acc[s][k];
            #pragma unroll
            for (int off = 32; off > 0; off >>= 1) v += __shfl_xor(v, off, 64);
            acc[s][k] = v;
        }

    // Analytic epilogue: lane 0 -> sample s0, lane 1 -> sample s0+1.
    if (lane < 2) {
        float z[NC];
        #pragma unroll
        for (int k = 0; k < NC; ++k) z[k] = (lane == 0) ? acc[0][k] : acc[1][k];

        float zm = z[0];
        #pragma unroll
        for (int k = 1; k < NC; ++k) zm = fmaxf(zm, z[k]);
        float e[NC], Zs = 0.0f;
        #pragma unroll
        for (int k = 0; k < NC; ++k) { e[k] = expf(z[k] - zm); Zs += e[k]; }
        const float inv = 1.0f / Zs;

        float sg[NC], p[NC], sq[NC], u[NC];
        #pragma unroll
        for (int k = 0; k < NC; ++k) {
            sg[k] = e[k] * inv;                 // softmax probs (sigma)
            p[k]  = kAlpha * sg[k] + kNumStab;  // stabilized probs
            sq[k] = sqrtf(p[k]);                // s
            u[k]  = sg[k] / sq[k];              // sigma / s
        }
        const float qd = 1.0f - sq[NM];

        // v = G*sigma, t = sigma^T G sigma
        float v[NC], t = 0.0f;
        #pragma unroll
        for (int k = 0; k < NC; ++k) {
            float a = 0.0f;
            #pragma unroll
            for (int j = 0; j < NC; ++j) a = fmaf(Gs[k * NC + j], sg[j], a);
            v[k] = a;
            t = fmaf(sg[k], a, t);
        }
        const float vM = v[NM], uM = u[NM];
        const float QMM = Gs[NC * NC - 1] - 2.0f * vM + t;

        float sumJ = 0.0f;
        #pragma unroll
        for (int i = 0; i < NM; ++i) {
            const float Qii = Gs[i * NC + i] - 2.0f * v[i] + t;
            const float QiM = Gs[i * NC + NM] - v[i] - vM + t;
            const float r = sq[i] / qd;
            sumJ += u[i] * u[i] * Qii
                  + 2.0f * u[i] * uM * r * QiM
                  + uM * uM * r * r * QMM;
        }
        const float jn = (kAlpha / qd) * sqrtf(fmaxf(sumJ, 0.0f));

        float ssum = 0.0f;
        #pragma unroll
        for (int k = 0; k < NC; ++k) ssum += sq[k];
        const float ac = fminf(1.0f, fmaxf(-1.0f, ssum * kInvSqrtC));
        const float delta = 2.0f * acosf(ac);

        float psum = 0.0f;
        #pragma unroll
        for (int k = 0; k < NM; ++k) psum += p[k];
        const float rho = (2.0f * qd - psum) / qd;

        const float a = jn - delta / (rho * kEps);
        regs[wv * 2 + lane] = (a > 0.0f) ? a : expm1f(a);
    }
    __syncthreads();
    if (tid == 0) {
        float bs = 0.0f;
        #pragma unroll
        for (int i = 0; i < 8; ++i) bs += regs[i];
        atomicAdd(out, bs * (1.0f / (float)NB));
    }
}

extern "C" void kernel_launch(void* const* d_in, const int* in_sizes, int n_in,
                              void* d_out, int out_size, void* d_ws, size_t ws_size,
                              hipStream_t stream) {
    const float* data = (const float*)d_in[0];
    const float* W    = (const float*)d_in[1];
    float* out = (float*)d_out;
    float* Wt  = (float*)d_ws;            // NC*ND floats (120 KB)
    float* G   = Wt + NC * ND;            // 100 floats

    // prep zeroes out (replaces hipMemsetAsync), transposes W, computes Gram.
    prep_kernel<<<30 + (NC * (NC + 1)) / 2, 256, 0, stream>>>(W, Wt, G, out);
    main_kernel<<<NB / 8, 256, 0, stream>>>(data, Wt, G, out);
}